// Round 4
// baseline (391.338 us; speedup 1.0000x reference)
//
#include <hip/hip_runtime.h>
#include <stdint.h>

// Workspace layout (~32.4 MB):
//   Wh    @ 0      : [2048][1024] bf16 (4 MB)  W_qv transposed, hi part
//   Wl    @ 4 MB   : [2048][1024] bf16 (4 MB)  W_qv transposed, lo part
//   qwsf  @ 8 MB   : [8][16][512][64] f32 (16 MB) q in full f32
//   vt    @ 24 MB  : [8][16][64][512] bf16 (8 MB) v transposed per head
//   poshi @ 32 MB          : [1088][64] bf16 (136 KB, rows>=1024 zero)
//   poslo @ 32 MB + 192 KB : [1088][64] bf16
//   maskf @ 32 MB + 384 KB : [4096] f32
//   rrbf  @ 32 MB + 400 KB : [1024] f32
//   rwbf  @ 32 MB + 404 KB : [1024] f32
//
// Inputs are f32 (deduced from npz sizes); runtime dtype dispatch kept as a
// safety net (mask all-ones: first u32 low-16 != 0 <=> bf16 inputs).
//
// Precision: logits must match f32 reference. Everything feeding the logits
// is computed via hi/lo bf16-split MFMA (error ~2^-18): x and W split for the
// q GEMM, q kept f32, q+bias and pos and K split in the attention kernel.
// v keeps single-precision-bf16 path (error ~0.005, inside threshold budget).

typedef __attribute__((ext_vector_type(8))) short s8v;
typedef __attribute__((ext_vector_type(4))) float f4v;

#define MFMA_BF16 __builtin_amdgcn_mfma_f32_16x16x32_bf16

__device__ __forceinline__ float bf2f(unsigned short s) {
  unsigned int u = ((unsigned int)s) << 16;
  float f;
  __builtin_memcpy(&f, &u, 4);
  return f;
}
__device__ __forceinline__ unsigned short f2bf(float f) {
  unsigned int u;
  __builtin_memcpy(&u, &f, 4);
  unsigned int r = (u + 0x7fffu + ((u >> 16) & 1u)) >> 16;
  return (unsigned short)r;
}
__device__ __forceinline__ bool is_bf16_in(const void* mask) {
  return (((const unsigned int*)mask)[0] & 0xFFFFu) != 0u;
}

// ---------------- normalize mask -> f32, biases -> f32 ----------------
__global__ __launch_bounds__(256) void k_prep(const void* __restrict__ mask,
                                              const void* __restrict__ rrb,
                                              const void* __restrict__ rwb,
                                              float* __restrict__ maskf,
                                              float* __restrict__ rrbf,
                                              float* __restrict__ rwbf) {
  const bool isb = is_bf16_in(mask);
  const int t = threadIdx.x;
  for (int i = t; i < 4096; i += 256)
    maskf[i] = isb ? bf2f(((const unsigned short*)mask)[i]) : ((const float*)mask)[i];
  for (int i = t; i < 1024; i += 256) {
    rrbf[i] = isb ? bf2f(((const unsigned short*)rrb)[i]) : ((const float*)rrb)[i];
    rwbf[i] = isb ? bf2f(((const unsigned short*)rwb)[i]) : ((const float*)rwb)[i];
  }
}

// ------- W transpose+split: W[1024][2048] -> Wh/Wl[2048][1024] bf16 -------
__global__ __launch_bounds__(256) void k_transpose(const void* __restrict__ W,
                                                   const void* __restrict__ mask,
                                                   unsigned short* __restrict__ Wh,
                                                   unsigned short* __restrict__ Wl) {
  __shared__ unsigned short th[64][65];
  __shared__ unsigned short tl[64][65];
  const bool isb = is_bf16_in(mask);
  const int n0 = blockIdx.x * 64;
  const int k0 = blockIdx.y * 64;
  const int t = threadIdx.x;
#pragma unroll
  for (int i = 0; i < 16; ++i) {
    int idx = t + i * 256;
    int kl = idx >> 6, nl = idx & 63;
    int src = (k0 + kl) * 2048 + n0 + nl;
    unsigned short hi, lo;
    if (isb) {
      hi = ((const unsigned short*)W)[src];
      lo = 0;
    } else {
      float v = ((const float*)W)[src];
      hi = f2bf(v);
      lo = f2bf(v - bf2f(hi));
    }
    th[nl][kl] = hi;
    tl[nl][kl] = lo;
  }
  __syncthreads();
#pragma unroll
  for (int i = 0; i < 16; ++i) {
    int idx = t + i * 256;
    int nl = idx >> 6, kl = idx & 63;
    Wh[(n0 + nl) * 1024 + k0 + kl] = th[nl][kl];
    Wl[(n0 + nl) * 1024 + k0 + kl] = tl[nl][kl];
  }
}

// ---------------- pos table: hi/lo split bf16, rows >= 1024 zeroed ----------------
__global__ __launch_bounds__(256) void k_pos(unsigned short* __restrict__ poshi,
                                             unsigned short* __restrict__ poslo) {
  int idx = blockIdx.x * 256 + threadIdx.x;
  if (idx >= 1088 * 64) return;
  int l = idx >> 6, i = idx & 63;
  unsigned short hi = 0, lo = 0;
  if (l < 1024) {
    int j = i & 31;
    float f = expf(-0.2971077539347156f * (float)j);  // -ln(10000)/31
    float ang = (float)(l - 512) * f;
    float v = (i < 32) ? sinf(ang) : cosf(ang);
    hi = f2bf(v);
    lo = f2bf(v - bf2f(hi));
  }
  poshi[idx] = hi;
  poslo[idx] = lo;
}

// ---- qv GEMM (split): x[4096][1024] x W[1024][2048] -> q (f32), v (bf16) ----
// grid.x 0..7 -> q columns (3 MFMAs, hi/lo exact); 8..15 -> v columns (1 MFMA)
__global__ __launch_bounds__(256, 2) void k_gemm_qv(const void* __restrict__ X,
                                                    const void* __restrict__ mask_raw,
                                                    const unsigned short* __restrict__ Wh,
                                                    const unsigned short* __restrict__ Wl,
                                                    float* __restrict__ qwsf,
                                                    unsigned short* __restrict__ vt) {
  __shared__ unsigned short Ah[128 * 40];
  __shared__ unsigned short Alo[128 * 40];
  __shared__ unsigned short Bh[128 * 40];
  __shared__ unsigned short Blo[128 * 40];
  const bool isb = is_bf16_in(mask_raw);
  const int m0 = blockIdx.y * 128;
  const int n0 = blockIdx.x * 128;
  const bool isq = (n0 < 1024);
  const int t = threadIdx.x;
  const int w = t >> 6, lane = t & 63;
  const int wr = w >> 1, wc = w & 1;
  const int l16 = lane & 15, g = lane >> 4;

  const int ca = t, cb = t + 256;
  const int ra = ca >> 2, ka = ca & 3, rb = cb >> 2, kb = cb & 3;

  f4v acc[4][4];
#pragma unroll
  for (int i = 0; i < 4; ++i)
#pragma unroll
    for (int j = 0; j < 4; ++j) acc[i][j] = (f4v){0.f, 0.f, 0.f, 0.f};

  for (int k0 = 0; k0 < 1024; k0 += 32) {
    // ---- load x chunks, split hi/lo in registers ----
    s8v xah, xal, xbh, xbl;
    if (isb) {
      xah = *(const s8v*)((const unsigned short*)X + (m0 + ra) * 1024 + k0 + ka * 8);
      xbh = *(const s8v*)((const unsigned short*)X + (m0 + rb) * 1024 + k0 + kb * 8);
#pragma unroll
      for (int j = 0; j < 8; ++j) { xal[j] = 0; xbl[j] = 0; }
    } else {
      const float* pa = (const float*)X + (m0 + ra) * 1024 + k0 + ka * 8;
      const float* pb = (const float*)X + (m0 + rb) * 1024 + k0 + kb * 8;
      f4v a0 = *(const f4v*)pa, a1_ = *(const f4v*)(pa + 4);
      f4v b0 = *(const f4v*)pb, b1_ = *(const f4v*)(pb + 4);
#pragma unroll
      for (int j = 0; j < 4; ++j) {
        unsigned short h0 = f2bf(a0[j]);
        xah[j] = (short)h0; xal[j] = (short)f2bf(a0[j] - bf2f(h0));
        unsigned short h1 = f2bf(a1_[j]);
        xah[j + 4] = (short)h1; xal[j + 4] = (short)f2bf(a1_[j] - bf2f(h1));
        unsigned short h2 = f2bf(b0[j]);
        xbh[j] = (short)h2; xbl[j] = (short)f2bf(b0[j] - bf2f(h2));
        unsigned short h3 = f2bf(b1_[j]);
        xbh[j + 4] = (short)h3; xbl[j + 4] = (short)f2bf(b1_[j] - bf2f(h3));
      }
    }
    s8v wha = *(const s8v*)&Wh[(n0 + ra) * 1024 + k0 + ka * 8];
    s8v whb = *(const s8v*)&Wh[(n0 + rb) * 1024 + k0 + kb * 8];
    s8v wla, wlb;
    if (isq) {
      wla = *(const s8v*)&Wl[(n0 + ra) * 1024 + k0 + ka * 8];
      wlb = *(const s8v*)&Wl[(n0 + rb) * 1024 + k0 + kb * 8];
    }
    __syncthreads();
    *(s8v*)&Ah[ra * 40 + ka * 8] = xah;
    *(s8v*)&Ah[rb * 40 + kb * 8] = xbh;
    *(s8v*)&Bh[ra * 40 + ka * 8] = wha;
    *(s8v*)&Bh[rb * 40 + kb * 8] = whb;
    if (isq) {
      *(s8v*)&Alo[ra * 40 + ka * 8] = xal;
      *(s8v*)&Alo[rb * 40 + kb * 8] = xbl;
      *(s8v*)&Blo[ra * 40 + ka * 8] = wla;
      *(s8v*)&Blo[rb * 40 + kb * 8] = wlb;
    }
    __syncthreads();
    s8v afh[4], bfh[4];
#pragma unroll
    for (int i = 0; i < 4; ++i) afh[i] = *(const s8v*)&Ah[(wr * 64 + i * 16 + l16) * 40 + g * 8];
#pragma unroll
    for (int j = 0; j < 4; ++j) bfh[j] = *(const s8v*)&Bh[(wc * 64 + j * 16 + l16) * 40 + g * 8];
    if (isq) {
      s8v afl[4], bfl[4];
#pragma unroll
      for (int i = 0; i < 4; ++i) afl[i] = *(const s8v*)&Alo[(wr * 64 + i * 16 + l16) * 40 + g * 8];
#pragma unroll
      for (int j = 0; j < 4; ++j) bfl[j] = *(const s8v*)&Blo[(wc * 64 + j * 16 + l16) * 40 + g * 8];
#pragma unroll
      for (int i = 0; i < 4; ++i)
#pragma unroll
        for (int j = 0; j < 4; ++j) {
          acc[i][j] = MFMA_BF16(afh[i], bfh[j], acc[i][j], 0, 0, 0);
          acc[i][j] = MFMA_BF16(afl[i], bfh[j], acc[i][j], 0, 0, 0);
          acc[i][j] = MFMA_BF16(afh[i], bfl[j], acc[i][j], 0, 0, 0);
        }
    } else {
#pragma unroll
      for (int i = 0; i < 4; ++i)
#pragma unroll
        for (int j = 0; j < 4; ++j) acc[i][j] = MFMA_BF16(afh[i], bfh[j], acc[i][j], 0, 0, 0);
    }
  }

#pragma unroll
  for (int i = 0; i < 4; ++i) {
#pragma unroll
    for (int j = 0; j < 4; ++j) {
      int col = n0 + wc * 64 + j * 16 + l16;
#pragma unroll
      for (int jj = 0; jj < 4; ++jj) {
        int row = m0 + wr * 64 + i * 16 + g * 4 + jj;
        int bb = row >> 9, l = row & 511;
        if (isq) {
          int hh = col >> 6, d = col & 63;
          qwsf[((bb * 16 + hh) * 512 + l) * 64 + d] = acc[i][j][jj];
        } else {
          int c2 = col - 1024;
          int hh = c2 >> 6, d = c2 & 63;
          vt[((bb * 16 + hh) * 64 + d) * 512 + l] = f2bf(acc[i][j][jj]);
        }
      }
    }
  }
}

// ---------------- fused relative attention ----------------
__global__ __launch_bounds__(256, 2) void k_attn(const void* __restrict__ X,
                                                 const float* __restrict__ maskf,
                                                 const float* __restrict__ qwsf,
                                                 const unsigned short* __restrict__ vt,
                                                 const unsigned short* __restrict__ poshi,
                                                 const unsigned short* __restrict__ poslo,
                                                 const float* __restrict__ rrbf,
                                                 const float* __restrict__ rwbf,
                                                 const void* __restrict__ mask_raw,
                                                 void* __restrict__ out) {
  __shared__ float S[64][68];
  __shared__ float A2b[64][132];
  __shared__ unsigned short P[64][72];
  __shared__ float scl[64];
  __shared__ float lsm[64];

  const bool isb = is_bf16_in(mask_raw);
  const int qt = blockIdx.x;
  const int bh = blockIdx.y;
  const int b = bh >> 4, h = bh & 15;
  const int q0 = qt << 6;
  const int t = threadIdx.x;
  const int w = t >> 6;
  const int lane = t & 63;
  const int l16 = lane & 15;
  const int g = lane >> 4;
  const int srow = t >> 2;
  const int sj = t & 3;
  const int rbase = (w << 4) + (g << 2);

  // Q fragments, hi/lo split, both biases folded (BD = (q + r_w_bias) . pos)
  s8v qrh[2], qrl[2], qwh[2], qwl[2];
  {
    const int qrow = q0 + (w << 4) + l16;
    const float* qb = &qwsf[((b * 16 + h) * 512 + qrow) * 64];
#pragma unroll
    for (int f = 0; f < 2; ++f) {
      int d0 = f * 32 + g * 8;
#pragma unroll
      for (int j = 0; j < 8; ++j) {
        float qf = qb[d0 + j];
        float s1 = qf + rrbf[h * 64 + d0 + j];
        float s2 = qf + rwbf[h * 64 + d0 + j];
        unsigned short h1 = f2bf(s1);
        unsigned short h2 = f2bf(s2);
        qrh[f][j] = (short)h1;
        qrl[f][j] = (short)f2bf(s1 - bf2f(h1));
        qwh[f][j] = (short)h2;
        qwl[f][j] = (short)f2bf(s2 - bf2f(h2));
      }
    }
  }

  f4v accO[4];
#pragma unroll
  for (int d = 0; d < 4; ++d) accO[d] = (f4v){0.f, 0.f, 0.f, 0.f};
  float mrun = -3.0e38f, lrun = 0.f;

  for (int kt = 0; kt < 8; ++kt) {
    const int k0 = kt << 6;
    const int l0t = k0 - q0 + 449;  // l = k - q + 512, band col c = kk - qq + 63

    f4v a1[4], a2[8];
#pragma unroll
    for (int ct = 0; ct < 4; ++ct) a1[ct] = (f4v){0.f, 0.f, 0.f, 0.f};
#pragma unroll
    for (int ct = 0; ct < 8; ++ct) a2[ct] = (f4v){0.f, 0.f, 0.f, 0.f};

#pragma unroll
    for (int f = 0; f < 2; ++f) {
      const int dk = f * 32 + g * 8;
#pragma unroll
      for (int ct = 0; ct < 4; ++ct) {  // A1 = Qr . K^T with K hi/lo from raw x
        s8v kh, klo;
        const int koff = (b * 512 + k0 + ct * 16 + l16) * 1024 + h * 64 + dk;
        if (isb) {
          kh = *(const s8v*)((const unsigned short*)X + koff);
#pragma unroll
          for (int j = 0; j < 8; ++j) klo[j] = 0;
        } else {
          const float* kp = (const float*)X + koff;
          f4v u0 = *(const f4v*)kp, u1 = *(const f4v*)(kp + 4);
#pragma unroll
          for (int j = 0; j < 4; ++j) {
            unsigned short h0 = f2bf(u0[j]);
            kh[j] = (short)h0; klo[j] = (short)f2bf(u0[j] - bf2f(h0));
            unsigned short h1 = f2bf(u1[j]);
            kh[j + 4] = (short)h1; klo[j + 4] = (short)f2bf(u1[j] - bf2f(h1));
          }
        }
        a1[ct] = MFMA_BF16(qrh[f], kh, a1[ct], 0, 0, 0);
        a1[ct] = MFMA_BF16(qrl[f], kh, a1[ct], 0, 0, 0);
        a1[ct] = MFMA_BF16(qrh[f], klo, a1[ct], 0, 0, 0);
      }
#pragma unroll
      for (int ct = 0; ct < 8; ++ct) {  // A2 = Qw . pos^T, both split
        s8v ph = *(const s8v*)&poshi[(l0t + ct * 16 + l16) * 64 + dk];
        s8v pl = *(const s8v*)&poslo[(l0t + ct * 16 + l16) * 64 + dk];
        a2[ct] = MFMA_BF16(qwh[f], ph, a2[ct], 0, 0, 0);
        a2[ct] = MFMA_BF16(qwh[f], pl, a2[ct], 0, 0, 0);
        a2[ct] = MFMA_BF16(qwl[f], ph, a2[ct], 0, 0, 0);
      }
    }

    // layout shuffle: MFMA accum -> row-major LDS
#pragma unroll
    for (int ct = 0; ct < 4; ++ct)
#pragma unroll
      for (int jj = 0; jj < 4; ++jj) S[rbase + jj][ct * 16 + l16] = a1[ct][jj];
#pragma unroll
    for (int ct = 0; ct < 8; ++ct)
#pragma unroll
      for (int jj = 0; jj < 4; ++jj) A2b[rbase + jj][ct * 16 + l16] = a2[ct][jj];
    __syncthreads();

    // diagonal gather + mask + online softmax (4 lanes per q-row)
    {
      float sv[16];
      const int kkb = sj * 16;
#pragma unroll
      for (int u = 0; u < 16; ++u) {
        int kk = kkb + u;
        float s = S[srow][kk] + A2b[srow][kk - srow + 63];
        s *= maskf[b * 512 + k0 + kk];
        if (s == 0.f) s = -__builtin_inff();
        sv[u] = s;
      }
      float pm = -3.0e38f;
#pragma unroll
      for (int u = 0; u < 16; ++u) pm = fmaxf(pm, sv[u]);
      pm = fmaxf(pm, __shfl_xor(pm, 1));
      pm = fmaxf(pm, __shfl_xor(pm, 2));
      float mnew = fmaxf(mrun, pm);
      float scale = __expf(mrun - mnew);
      float ps = 0.f;
#pragma unroll
      for (int u = 0; u < 16; ++u) {
        float p = __expf(sv[u] - mnew);
        unsigned short pb = f2bf(p);
        ps += bf2f(pb);  // denominator consistent with bf16 numerator
        P[srow][kkb + u] = pb;
      }
      ps += __shfl_xor(ps, 1);
      ps += __shfl_xor(ps, 2);
      lrun = lrun * scale + ps;
      mrun = mnew;
      if (sj == 0) scl[srow] = scale;
    }
    __syncthreads();

    // O rescale + PV MFMA (V fragments direct from transposed global vt)
    {
      float sc[4];
#pragma unroll
      for (int jj = 0; jj < 4; ++jj) sc[jj] = scl[rbase + jj];
#pragma unroll
      for (int d = 0; d < 4; ++d) {
#pragma unroll
        for (int jj = 0; jj < 4; ++jj) accO[d][jj] *= sc[jj];
      }
#pragma unroll
      for (int ks = 0; ks < 2; ++ks) {
        s8v pf = *(const s8v*)&P[(w << 4) + l16][ks * 32 + g * 8];
#pragma unroll
        for (int d = 0; d < 4; ++d) {
          s8v vf = *(const s8v*)&vt[((b * 16 + h) * 64 + d * 16 + l16) * 512 + k0 + ks * 32 + g * 8];
          accO[d] = MFMA_BF16(pf, vf, accO[d], 0, 0, 0);
        }
      }
    }
    __syncthreads();
  }

  if (sj == 0) lsm[srow] = lrun;
  __syncthreads();
  float inv[4];
#pragma unroll
  for (int jj = 0; jj < 4; ++jj) inv[jj] = 1.0f / lsm[rbase + jj];
#pragma unroll
  for (int d = 0; d < 4; ++d) {
#pragma unroll
    for (int jj = 0; jj < 4; ++jj) {
      int row = q0 + rbase + jj;
      int idx = (b * 512 + row) * 1024 + h * 64 + d * 16 + l16;
      float val = accO[d][jj] * inv[jj];
      if (isb) ((unsigned short*)out)[idx] = f2bf(val);
      else ((float*)out)[idx] = val;
    }
  }
}

extern "C" void kernel_launch(void* const* d_in, const int* in_sizes, int n_in,
                              void* d_out, int out_size, void* d_ws, size_t ws_size,
                              hipStream_t stream) {
  (void)in_sizes; (void)n_in; (void)out_size; (void)ws_size;
  const void* x    = d_in[0];
  const void* mask = d_in[1];
  const void* wqv  = d_in[2];
  const void* rrb  = d_in[3];
  const void* rwb  = d_in[4];

  char* ws = (char*)d_ws;
  unsigned short* Wh    = (unsigned short*)(ws);
  unsigned short* Wl    = (unsigned short*)(ws + (4u << 20));
  float*          qwsf  = (float*)(ws + (8u << 20));
  unsigned short* vt    = (unsigned short*)(ws + (24u << 20));
  unsigned short* poshi = (unsigned short*)(ws + (32u << 20));
  unsigned short* poslo = (unsigned short*)(ws + (32u << 20) + (192u << 10));
  float* maskf          = (float*)(ws + (32u << 20) + (384u << 10));
  float* rrbf           = (float*)(ws + (32u << 20) + (400u << 10));
  float* rwbf           = (float*)(ws + (32u << 20) + (404u << 10));

  k_prep<<<dim3(1), 256, 0, stream>>>(mask, rrb, rwb, maskf, rrbf, rwbf);
  k_transpose<<<dim3(32, 16), 256, 0, stream>>>(wqv, mask, Wh, Wl);
  k_pos<<<dim3(272), 256, 0, stream>>>(poshi, poslo);
  k_gemm_qv<<<dim3(16, 32), 256, 0, stream>>>(x, mask, Wh, Wl, qwsf, vt);
  k_attn<<<dim3(8, 128), 256, 0, stream>>>(x, maskf, qwsf, vt, poshi, poslo, rrbf, rwbf, mask, (void*)d_out);
}